// Round 10
// baseline (245.008 us; speedup 1.0000x reference)
//
#include <hip/hip_runtime.h>
#include <hip/hip_bf16.h>
#include <math.h>

#define B 4096
#define NF 50
#define BN_EPS 1e-3f
#define ROWS 16

typedef float f32x4 __attribute__((ext_vector_type(4)));
typedef __bf16 bf16x8 __attribute__((ext_vector_type(8)));
#define MFMA __builtin_amdgcn_mfma_f32_16x16x32_bf16

__device__ __forceinline__ unsigned short f2b(float x) {
  unsigned u = __float_as_uint(x);
  return (unsigned short)((u + 0x7FFFu + ((u >> 16) & 1u)) >> 16);  // RNE
}
__device__ __forceinline__ unsigned packbf(float a, float b) {
  return ((unsigned)f2b(b) << 16) | (unsigned)f2b(a);
}
__device__ __forceinline__ float bs2f(unsigned short u) {
  return __uint_as_float(((unsigned)u) << 16);
}
// load 8 consecutive fp32, convert -> bf16x8 fragment (RNE)
__device__ __forceinline__ bf16x8 ld_bf8(const float* p) {
  float4 a = *(const float4*)p, b = *(const float4*)(p + 4);
  union { unsigned u[4]; bf16x8 v; } r;
  r.u[0] = packbf(a.x, a.y); r.u[1] = packbf(a.z, a.w);
  r.u[2] = packbf(b.x, b.y); r.u[3] = packbf(b.z, b.w);
  return r.v;
}
// load 8 fp32 at stride (W[k][n], k varying), convert -> bf16x8
__device__ __forceinline__ bf16x8 ld_bf8_strided(const float* p, int stride) {
  float f[8];
#pragma unroll
  for (int j = 0; j < 8; ++j) f[j] = p[j * stride];
  union { unsigned u[4]; bf16x8 v; } r;
  r.u[0] = packbf(f[0], f[1]); r.u[1] = packbf(f[2], f[3]);
  r.u[2] = packbf(f[4], f[5]); r.u[3] = packbf(f[6], f[7]);
  return r.v;
}

// ===========================================================================
// SINGLE dispatch: 256 blocks x 512 threads (8 waves), 16 rows/block,
// 6 barriers. feats[16][3200] staged once in LDS; waves then run independent
// barrier-free K-loops (w0-3 l_z + l_p_in, w4-7 l_p_out). All fp32 operands
// converted to bf16 in-register at fragment load (no prep kernel, no ws).
__global__ __launch_bounds__(512) void pnn_all(
    const float* __restrict__ fv, const int* __restrict__ idx,
    const float* __restrict__ emb, const float* __restrict__ theta,
    const float* __restrict__ ls, const float* __restrict__ qw,
    const float* __restrict__ W0, const float* __restrict__ b0p,
    const float* __restrict__ g0p, const float* __restrict__ be0p,
    const float* __restrict__ m0p, const float* __restrict__ v0p,
    const float* __restrict__ W1, const float* __restrict__ b1p,
    const float* __restrict__ g1p, const float* __restrict__ be1p,
    const float* __restrict__ m1p, const float* __restrict__ v1p,
    const float* __restrict__ W2, const float* __restrict__ b2p,
    const float* __restrict__ g2p, const float* __restrict__ be2p,
    const float* __restrict__ m2p, const float* __restrict__ v2p,
    const float* __restrict__ Wout, const float* __restrict__ boutp,
    float* __restrict__ out)
{
  __shared__ unsigned short feats[25 * 16 * 136];  // 108.8 KB; aliased later
  __shared__ int   idx_s[ROWS * NF];
  __shared__ float fv_s[ROWS * NF];
  __shared__ float s_s[ROWS * 68];
  __shared__ float sq_s[ROWS * 64];
  __shared__ unsigned short x_s[ROWS * 200];       // [16][192+8]

  unsigned short* h0_s = feats;                    // [16][520]
  unsigned short* h1_s = feats + 8320;             // [16][264]
  unsigned short* h2_s = feats + 12544;            // [16][136]

  const int t    = threadIdx.x;
  const int w    = t >> 6;          // wave 0..7
  const int l    = t & 63;
  const int m16  = l & 15;
  const int qoff = (l >> 4) * 8;
  const int b0   = blockIdx.x * ROWS;

  // ---------------- phase 0: idx/fv ----------------
  for (int i = t; i < ROWS * NF; i += 512) {
    idx_s[i] = idx[b0 * NF + i];
    fv_s[i]  = fv[b0 * NF + i];
  }
  __syncthreads();   // barrier 1

  // ---------------- phase 1: gather feats, s, sq (no barriers inside) -----
  {
    const int row = t >> 5;          // half-wave = one batch row
    const int m2  = (t & 31) * 2;    // two m columns per lane
    float s0 = 0.f, s1 = 0.f;
#pragma unroll 5
    for (int c = 0; c < 25; ++c) {
      int n0 = 2 * c, n1 = n0 + 1;
      int iv0 = idx_s[row * NF + n0], iv1 = idx_s[row * NF + n1];
      float f0 = fv_s[row * NF + n0], f1 = fv_s[row * NF + n1];
      float2 e0 = *(const float2*)(emb + (size_t)iv0 * 64 + m2);
      float2 e1 = *(const float2*)(emb + (size_t)iv1 * 64 + m2);
      float p00 = f0 * e0.x, p01 = f0 * e0.y;
      float p10 = f1 * e1.x, p11 = f1 * e1.y;
      unsigned short* fc = feats + c * 2176 + row * 136;
      *(unsigned*)&fc[m2]      = packbf(p00, p01);
      *(unsigned*)&fc[64 + m2] = packbf(p10, p11);
      s0 += p00 + p10; s1 += p01 + p11;
      float q0 = p00 * p00 + p01 * p01;
      float q1 = p10 * p10 + p11 * p11;
      q0 += __shfl_xor(q0, 16); q0 += __shfl_xor(q0, 8); q0 += __shfl_xor(q0, 4);
      q0 += __shfl_xor(q0, 2);  q0 += __shfl_xor(q0, 1);
      q1 += __shfl_xor(q1, 16); q1 += __shfl_xor(q1, 8); q1 += __shfl_xor(q1, 4);
      q1 += __shfl_xor(q1, 2);  q1 += __shfl_xor(q1, 1);
      if ((t & 31) == 0) { sq_s[row * 64 + n0] = q0; sq_s[row * 64 + n1] = q1; }
    }
    float2 sv; sv.x = s0; sv.y = s1;
    *(float2*)&s_s[row * 68 + m2] = sv;
  }
  __syncthreads();   // barrier 2

  // ---------------- phase 2: independent per-wave GEMMs -------------------
  if (w < 4) {
    // l_z: d-tile [16w, 16w+16), K=3200, barrier-free; B from fp32 ls
    const int dt = w;
    f32x4 a0v = {0.f, 0.f, 0.f, 0.f}, a1v = {0.f, 0.f, 0.f, 0.f};
    const float* lp0 = ls + (size_t)(dt * 16 + m16) * 3200 + qoff;
    for (int c = 0; c < 25; ++c) {
      const unsigned short* fc = feats + c * 2176 + m16 * 136 + qoff;
      const float* lp = lp0 + c * 128;
#pragma unroll
      for (int s = 0; s < 4; ++s) {
        bf16x8 av = *(const bf16x8*)(fc + s * 32);
        bf16x8 bv = ld_bf8(lp + s * 32);
        if (s & 1) a1v = MFMA(av, bv, a1v, 0, 0, 0);
        else       a0v = MFMA(av, bv, a0v, 0, 0, 0);
      }
    }
#pragma unroll
    for (int r = 0; r < 4; ++r)
      x_s[((l >> 4) * 4 + r) * 200 + dt * 16 + m16] = f2b(a0v[r] + a1v[r]);
    // l_p_in: d = dt*16+m16, 4 rows per lane
    {
      int d = dt * 16 + m16;
      float acc[4] = {0.f, 0.f, 0.f, 0.f};
      for (int n = 0; n < NF; ++n) {
        float th = theta[d * NF + n];
        float th2 = th * th;
#pragma unroll
        for (int r = 0; r < 4; ++r)
          acc[r] += sq_s[((l >> 4) * 4 + r) * 64 + n] * th2;
      }
#pragma unroll
      for (int r = 0; r < 4; ++r)
        x_s[((l >> 4) * 4 + r) * 200 + 64 + d] = f2b(acc[r]);
    }
  } else {
    // l_p_out: d-tile [16(w-4), ...), K=4096, P in-register, B from fp32 qw
    const int dt = w - 4;
    const int row = m16;
    const int nb = qoff;
    float sn[16];
    *(float4*)&sn[0]  = *(const float4*)&s_s[row * 68 + nb];
    *(float4*)&sn[4]  = *(const float4*)&s_s[row * 68 + nb + 4];
    *(float4*)&sn[8]  = *(const float4*)&s_s[row * 68 + 32 + nb];
    *(float4*)&sn[12] = *(const float4*)&s_s[row * 68 + 32 + nb + 4];
    f32x4 a0v = {0.f, 0.f, 0.f, 0.f}, a1v = {0.f, 0.f, 0.f, 0.f};
    const float* qp0 = qw + (size_t)(dt * 16 + m16) * 4096 + qoff;
    for (int m = 0; m < 64; ++m) {
      float sm = s_s[row * 68 + m];
      union { unsigned u[4]; bf16x8 v; } af0, af1;
#pragma unroll
      for (int j = 0; j < 4; ++j) {
        af0.u[j] = packbf(sm * sn[2 * j],     sm * sn[2 * j + 1]);
        af1.u[j] = packbf(sm * sn[8 + 2 * j], sm * sn[8 + 2 * j + 1]);
      }
      const float* qp = qp0 + m * 64;
      bf16x8 b0v = ld_bf8(qp);
      bf16x8 b1v = ld_bf8(qp + 32);
      a0v = MFMA(af0.v, b0v, a0v, 0, 0, 0);
      a1v = MFMA(af1.v, b1v, a1v, 0, 0, 0);
    }
#pragma unroll
    for (int r = 0; r < 4; ++r)
      x_s[((l >> 4) * 4 + r) * 200 + 128 + dt * 16 + m16] = f2b(a0v[r] + a1v[r]);
  }
  __syncthreads();   // barrier 3 (feats dead; h-buffers alias it)

  // ---------------- phase 3: MLP (W-frags strided from fp32) --------------
  // layer 0: 192 -> 512, 4 n-tiles per wave
  {
    int ar = m16 * 200 + qoff;
    bf16x8 xa[6];
#pragma unroll
    for (int kc = 0; kc < 6; ++kc) xa[kc] = *(const bf16x8*)&x_s[ar + kc * 32];
    for (int j = 0; j < 4; ++j) {
      int n0 = (w * 4 + j) * 16;
      f32x4 ha = {0.f, 0.f, 0.f, 0.f}, hb = {0.f, 0.f, 0.f, 0.f};
#pragma unroll
      for (int kc = 0; kc < 6; ++kc) {
        bf16x8 bv = ld_bf8_strided(W0 + (size_t)(kc * 32 + qoff) * 512 + n0 + m16, 512);
        if (kc & 1) hb = MFMA(xa[kc], bv, hb, 0, 0, 0);
        else        ha = MFMA(xa[kc], bv, ha, 0, 0, 0);
      }
      int n = n0 + m16;
      float sc = g0p[n] * rsqrtf(v0p[n] + BN_EPS);
      float sh = be0p[n] + (b0p[n] - m0p[n]) * sc;
#pragma unroll
      for (int r = 0; r < 4; ++r) {
        float v = fmaxf((ha[r] + hb[r]) * sc + sh, 0.f);
        h0_s[((l >> 4) * 4 + r) * 520 + n] = f2b(v);
      }
    }
  }
  __syncthreads();   // barrier 4

  // layer 1: 512 -> 256, 2 n-tiles per wave
  for (int j = 0; j < 2; ++j) {
    int n0 = (w * 2 + j) * 16;
    int ar = m16 * 520 + qoff;
    f32x4 ha = {0.f, 0.f, 0.f, 0.f}, hb = {0.f, 0.f, 0.f, 0.f};
#pragma unroll
    for (int kc = 0; kc < 16; ++kc) {
      bf16x8 av = *(const bf16x8*)&h0_s[ar + kc * 32];
      bf16x8 bv = ld_bf8_strided(W1 + (size_t)(kc * 32 + qoff) * 256 + n0 + m16, 256);
      if (kc & 1) hb = MFMA(av, bv, hb, 0, 0, 0);
      else        ha = MFMA(av, bv, ha, 0, 0, 0);
    }
    int n = n0 + m16;
    float sc = g1p[n] * rsqrtf(v1p[n] + BN_EPS);
    float sh = be1p[n] + (b1p[n] - m1p[n]) * sc;
#pragma unroll
    for (int r = 0; r < 4; ++r) {
      float v = fmaxf((ha[r] + hb[r]) * sc + sh, 0.f);
      h1_s[((l >> 4) * 4 + r) * 264 + n] = f2b(v);
    }
  }
  __syncthreads();   // barrier 5

  // layer 2: 256 -> 128, 1 n-tile per wave
  {
    int n0 = w * 16;
    int ar = m16 * 264 + qoff;
    f32x4 ha = {0.f, 0.f, 0.f, 0.f}, hb = {0.f, 0.f, 0.f, 0.f};
#pragma unroll
    for (int kc = 0; kc < 8; ++kc) {
      bf16x8 av = *(const bf16x8*)&h1_s[ar + kc * 32];
      bf16x8 bv = ld_bf8_strided(W2 + (size_t)(kc * 32 + qoff) * 128 + n0 + m16, 128);
      if (kc & 1) hb = MFMA(av, bv, hb, 0, 0, 0);
      else        ha = MFMA(av, bv, ha, 0, 0, 0);
    }
    int n = n0 + m16;
    float sc = g2p[n] * rsqrtf(v2p[n] + BN_EPS);
    float sh = be2p[n] + (b2p[n] - m2p[n]) * sc;
#pragma unroll
    for (int r = 0; r < 4; ++r) {
      float v = fmaxf((ha[r] + hb[r]) * sc + sh, 0.f);
      h2_s[((l >> 4) * 4 + r) * 136 + n] = f2b(v);
    }
  }
  __syncthreads();   // barrier 6

  // output: sigmoid(h2 @ Wout + bout)
  if (t < 128) {
    int bb = t >> 3, seg = t & 7;
    float a = 0.f;
#pragma unroll
    for (int j = 0; j < 16; ++j) {
      int k = seg * 16 + j;
      a += bs2f(h2_s[bb * 136 + k]) * Wout[k];
    }
    a += __shfl_xor(a, 4); a += __shfl_xor(a, 2); a += __shfl_xor(a, 1);
    if (seg == 0) out[b0 + bb] = 1.f / (1.f + expf(-(a + boutp[0])));
  }
}

// ===========================================================================
extern "C" void kernel_launch(void* const* d_in, const int* in_sizes, int n_in,
                              void* d_out, int out_size, void* d_ws, size_t ws_size,
                              hipStream_t stream)
{
  (void)in_sizes; (void)n_in; (void)out_size; (void)d_ws; (void)ws_size;

  pnn_all<<<B / ROWS, 512, 0, stream>>>(
      (const float*)d_in[0], (const int*)d_in[1], (const float*)d_in[2],
      (const float*)d_in[4], (const float*)d_in[3], (const float*)d_in[5],
      (const float*)d_in[6],  (const float*)d_in[7],  (const float*)d_in[8],
      (const float*)d_in[9],  (const float*)d_in[10], (const float*)d_in[11],
      (const float*)d_in[12], (const float*)d_in[13], (const float*)d_in[14],
      (const float*)d_in[15], (const float*)d_in[16], (const float*)d_in[17],
      (const float*)d_in[18], (const float*)d_in[19], (const float*)d_in[20],
      (const float*)d_in[21], (const float*)d_in[22], (const float*)d_in[23],
      (const float*)d_in[24], (const float*)d_in[25],
      (float*)d_out);
}

// Round 11
// 228.595 us; speedup vs baseline: 1.0718x; 1.0718x over previous
//
#include <hip/hip_runtime.h>
#include <hip/hip_bf16.h>
#include <math.h>

#define B 4096
#define NF 50
#define BN_EPS 1e-3f
#define ROWS 8

typedef float f32x4 __attribute__((ext_vector_type(4)));
typedef __bf16 bf16x8 __attribute__((ext_vector_type(8)));
#define MFMA __builtin_amdgcn_mfma_f32_16x16x32_bf16

__device__ __forceinline__ unsigned short f2b(float x) {
  unsigned u = __float_as_uint(x);
  return (unsigned short)((u + 0x7FFFu + ((u >> 16) & 1u)) >> 16);  // RNE
}
__device__ __forceinline__ unsigned packbf(float a, float b) {
  return ((unsigned)f2b(b) << 16) | (unsigned)f2b(a);
}
__device__ __forceinline__ float bs2f(unsigned short u) {
  return __uint_as_float(((unsigned)u) << 16);
}

// ---- workspace (unsigned short elems), all B-operands n-major/k-contig ----
#define WS_LS  0        // [64][3200]
#define WS_QW  204800   // [64][4096]
#define WS_W0  466944   // [512][192]
#define WS_W1  565248   // [256][512]
#define WS_W2  696320   // [128][256]

// ===========================================================================
// prep (r9 verbatim, proven): bf16 convert + W transposes via LDS tiles
__global__ __launch_bounds__(256) void prep(
    const float* __restrict__ ls, const float* __restrict__ qw,
    const float* __restrict__ W0, const float* __restrict__ W1,
    const float* __restrict__ W2, unsigned short* __restrict__ ws)
{
  int bid = blockIdx.x, t = threadIdx.x;
  if (bid < 228) {                // ls (100 blocks) + qw (128 blocks)
    int o = (bid * 256 + t) * 8;
    const float* src = (o < 204800) ? (ls + o) : (qw + (o - 204800));
    float4 a = *(const float4*)src, b = *(const float4*)(src + 4);
    int4 v = {(int)packbf(a.x, a.y), (int)packbf(a.z, a.w),
              (int)packbf(b.x, b.y), (int)packbf(b.z, b.w)};
    *(int4*)&ws[o] = v;
    return;
  }
  __shared__ unsigned short sh[64 * 72];
  int id = bid - 228;
  const float* W; int K, Ncols, kt, nt, wofs;
  if (id < 24)      { W = W0; K = 192; Ncols = 512; kt = id >> 3; nt = id & 7;  wofs = WS_W0; }
  else if (id < 56) { int j = id - 24; W = W1; K = 512; Ncols = 256; kt = j >> 2; nt = j & 3; wofs = WS_W1; }
  else              { int j = id - 56; W = W2; K = 256; Ncols = 128; kt = j >> 1; nt = j & 1; wofs = WS_W2; }
  int k0 = kt * 64, n0 = nt * 64;
  {
    int r = t >> 2, cs = (t & 3) * 16;
    const float* src = W + (size_t)(k0 + r) * Ncols + n0 + cs;
    float4 a = *(const float4*)src, b = *(const float4*)(src + 4);
    float4 c = *(const float4*)(src + 8), d = *(const float4*)(src + 12);
    unsigned short* dst = &sh[r * 72 + cs];
    *(int4*)dst = int4{(int)packbf(a.x, a.y), (int)packbf(a.z, a.w),
                       (int)packbf(b.x, b.y), (int)packbf(b.z, b.w)};
    *(int4*)(dst + 8) = int4{(int)packbf(c.x, c.y), (int)packbf(c.z, c.w),
                             (int)packbf(d.x, d.y), (int)packbf(d.z, d.w)};
  }
  __syncthreads();
  {
    int nr = t >> 2, ks = (t & 3) * 16;
    unsigned short vbuf[16];
#pragma unroll
    for (int j = 0; j < 16; ++j) vbuf[j] = sh[(ks + j) * 72 + nr];
    unsigned short* dst = &ws[wofs + (size_t)(n0 + nr) * K + k0 + ks];
    *(int4*)dst = *(int4*)&vbuf[0];
    *(int4*)(dst + 8) = *(int4*)&vbuf[8];
  }
}

// ===========================================================================
// 512 blocks x 512 threads (8 waves), 8 rows/block, 6 barriers (r9 structure).
// LDS ~76 KB -> 2 resident blocks/CU (16 waves/CU). A-rows duplicate via &7.
// Gather: wave w = batch row w, lane = m. Independent per-wave GEMM K-loops.
__global__ __launch_bounds__(512, 4) void pnn_main(
    const float* __restrict__ fv, const int* __restrict__ idx,
    const float* __restrict__ emb, const float* __restrict__ theta,
    const unsigned short* __restrict__ ws,
    const float* __restrict__ b0p, const float* __restrict__ g0p,
    const float* __restrict__ be0p, const float* __restrict__ m0p,
    const float* __restrict__ v0p,
    const float* __restrict__ b1p, const float* __restrict__ g1p,
    const float* __restrict__ be1p, const float* __restrict__ m1p,
    const float* __restrict__ v1p,
    const float* __restrict__ b2p, const float* __restrict__ g2p,
    const float* __restrict__ be2p, const float* __restrict__ m2p,
    const float* __restrict__ v2p,
    const float* __restrict__ Wout, const float* __restrict__ boutp,
    float* __restrict__ out)
{
  __shared__ unsigned short feats[25 * ROWS * 136];  // 54.4 KB; aliased later
  __shared__ int   idx_s[ROWS * NF];
  __shared__ float fv_s[ROWS * NF];
  __shared__ float th2_s[64 * NF];
  __shared__ float s_s[ROWS * 68];
  __shared__ float sq_s[ROWS * 64];
  __shared__ unsigned short x_s[ROWS * 200];         // [8][192+8]

  unsigned short* h0_s = feats;                      // [8][520] = 4160
  unsigned short* h1_s = feats + 4160;               // [8][264] = 2112
  unsigned short* h2_s = feats + 6272;               // [8][136] = 1088

  const unsigned short* lsb = ws + WS_LS;
  const unsigned short* qwb = ws + WS_QW;
  const unsigned short* w0t = ws + WS_W0;
  const unsigned short* w1t = ws + WS_W1;
  const unsigned short* w2t = ws + WS_W2;

  const int t    = threadIdx.x;
  const int w    = t >> 6;          // wave 0..7
  const int l    = t & 63;
  const int m16  = l & 15;
  const int qoff = (l >> 4) * 8;
  const int b0   = blockIdx.x * ROWS;

  // ---------------- phase 0: idx/fv/theta^2 ----------------
  for (int i = t; i < ROWS * NF; i += 512) {
    idx_s[i] = idx[b0 * NF + i];
    fv_s[i]  = fv[b0 * NF + i];
  }
  for (int i = t; i < 64 * NF; i += 512) { float v = theta[i]; th2_s[i] = v * v; }
  __syncthreads();   // barrier 1

  // ---------------- phase 1: gather feats, s, sq (wave = row, lane = m) ----
  {
    float s0 = 0.f;
#pragma unroll 2
    for (int n = 0; n < NF; ++n) {
      int iv = idx_s[w * NF + n];
      float fvv = fv_s[w * NF + n];
      float p = fvv * emb[(size_t)iv * 64 + l];
      feats[(n >> 1) * (ROWS * 136) + w * 136 + (n & 1) * 64 + l] = f2b(p);
      s0 += p;
      float q = p * p;
      q += __shfl_xor(q, 32); q += __shfl_xor(q, 16); q += __shfl_xor(q, 8);
      q += __shfl_xor(q, 4);  q += __shfl_xor(q, 2);  q += __shfl_xor(q, 1);
      if (l == 0) sq_s[w * 64 + n] = q;
    }
    s_s[w * 68 + l] = s0;
  }
  __syncthreads();   // barrier 2

  // ---------------- phase 2: independent per-wave GEMMs -------------------
  if (w < 4) {
    // l_z: d-tile [16w,16w+16), K=3200, barrier-free; A rows dup via &7
    const int dt = w;
    f32x4 a0v = {0.f, 0.f, 0.f, 0.f}, a1v = {0.f, 0.f, 0.f, 0.f};
    const unsigned short* lp0 = lsb + (size_t)(dt * 16 + m16) * 3200 + qoff;
    const int arow = (m16 & 7) * 136 + qoff;
    for (int c = 0; c < 25; ++c) {
      const unsigned short* fc = feats + c * (ROWS * 136) + arow;
      const unsigned short* lp = lp0 + c * 128;
#pragma unroll
      for (int s = 0; s < 4; ++s) {
        bf16x8 av = *(const bf16x8*)(fc + s * 32);
        bf16x8 bv = *(const bf16x8*)(lp + s * 32);
        if (s & 1) a1v = MFMA(av, bv, a1v, 0, 0, 0);
        else       a0v = MFMA(av, bv, a0v, 0, 0, 0);
      }
    }
    if (l < 32) {
#pragma unroll
      for (int r = 0; r < 4; ++r)
        x_s[((l >> 4) * 4 + r) * 200 + dt * 16 + m16] = f2b(a0v[r] + a1v[r]);
    }
    // l_p_in: d = dt*16+m16, rows 0..7 handled by lanes l<32
    if (l < 32) {
      int d = dt * 16 + m16;
      float acc[4] = {0.f, 0.f, 0.f, 0.f};
      for (int n = 0; n < NF; ++n) {
        float th2 = th2_s[d * NF + n];
#pragma unroll
        for (int r = 0; r < 4; ++r)
          acc[r] += sq_s[((l >> 4) * 4 + r) * 64 + n] * th2;
      }
#pragma unroll
      for (int r = 0; r < 4; ++r)
        x_s[((l >> 4) * 4 + r) * 200 + 64 + d] = f2b(acc[r]);
    }
  } else {
    // l_p_out: d-tile [16(w-4),...), K=4096, P in-register from s_s
    const int dt = w - 4;
    const int row = m16 & 7;
    const int nb = qoff;
    float sn[16];
    *(float4*)&sn[0]  = *(const float4*)&s_s[row * 68 + nb];
    *(float4*)&sn[4]  = *(const float4*)&s_s[row * 68 + nb + 4];
    *(float4*)&sn[8]  = *(const float4*)&s_s[row * 68 + 32 + nb];
    *(float4*)&sn[12] = *(const float4*)&s_s[row * 68 + 32 + nb + 4];
    f32x4 a0v = {0.f, 0.f, 0.f, 0.f}, a1v = {0.f, 0.f, 0.f, 0.f};
    const unsigned short* qp0 = qwb + (size_t)(dt * 16 + m16) * 4096 + qoff;
    for (int m = 0; m < 64; ++m) {
      float sm = s_s[row * 68 + m];
      union { unsigned u[4]; bf16x8 v; } af0, af1;
#pragma unroll
      for (int j = 0; j < 4; ++j) {
        af0.u[j] = packbf(sm * sn[2 * j],     sm * sn[2 * j + 1]);
        af1.u[j] = packbf(sm * sn[8 + 2 * j], sm * sn[8 + 2 * j + 1]);
      }
      const unsigned short* qp = qp0 + m * 64;
      bf16x8 b0v = *(const bf16x8*)qp;
      bf16x8 b1v = *(const bf16x8*)(qp + 32);
      a0v = MFMA(af0.v, b0v, a0v, 0, 0, 0);
      a1v = MFMA(af1.v, b1v, a1v, 0, 0, 0);
    }
    if (l < 32) {
#pragma unroll
      for (int r = 0; r < 4; ++r)
        x_s[((l >> 4) * 4 + r) * 200 + 128 + dt * 16 + m16] = f2b(a0v[r] + a1v[r]);
    }
  }
  __syncthreads();   // barrier 3 (feats dead; h-buffers alias it)

  // ---------------- phase 3: MLP (B-frags from L2-resident bf16 ws) -------
  // layer 0: 192 -> 512, 4 n-tiles per wave
  {
    int ar = (m16 & 7) * 200 + qoff;
    bf16x8 xa[6];
#pragma unroll
    for (int kc = 0; kc < 6; ++kc) xa[kc] = *(const bf16x8*)&x_s[ar + kc * 32];
    for (int j = 0; j < 4; ++j) {
      int n0 = (w * 4 + j) * 16;
      const unsigned short* wp = w0t + (size_t)(n0 + m16) * 192 + qoff;
      f32x4 ha = {0.f, 0.f, 0.f, 0.f}, hb = {0.f, 0.f, 0.f, 0.f};
#pragma unroll
      for (int kc = 0; kc < 6; ++kc) {
        bf16x8 bv = *(const bf16x8*)(wp + kc * 32);
        if (kc & 1) hb = MFMA(xa[kc], bv, hb, 0, 0, 0);
        else        ha = MFMA(xa[kc], bv, ha, 0, 0, 0);
      }
      if (l < 32) {
        int n = n0 + m16;
        float sc = g0p[n] * rsqrtf(v0p[n] + BN_EPS);
        float sh = be0p[n] + (b0p[n] - m0p[n]) * sc;
#pragma unroll
        for (int r = 0; r < 4; ++r) {
          float v = fmaxf((ha[r] + hb[r]) * sc + sh, 0.f);
          h0_s[((l >> 4) * 4 + r) * 520 + n] = f2b(v);
        }
      }
    }
  }
  __syncthreads();   // barrier 4

  // layer 1: 512 -> 256, 2 n-tiles per wave
  for (int j = 0; j < 2; ++j) {
    int n0 = (w * 2 + j) * 16;
    const unsigned short* wp = w1t + (size_t)(n0 + m16) * 512 + qoff;
    int ar = (m16 & 7) * 520 + qoff;
    f32x4 ha = {0.f, 0.f, 0.f, 0.f}, hb = {0.f, 0.f, 0.f, 0.f};
#pragma unroll
    for (int kc = 0; kc < 16; ++kc) {
      bf16x8 av = *(const bf16x8*)&h0_s[ar + kc * 32];
      bf16x8 bv = *(const bf16x8*)(wp + kc * 32);
      if (kc & 1) hb = MFMA(av, bv, hb, 0, 0, 0);
      else        ha = MFMA(av, bv, ha, 0, 0, 0);
    }
    if (l < 32) {
      int n = n0 + m16;
      float sc = g1p[n] * rsqrtf(v1p[n] + BN_EPS);
      float sh = be1p[n] + (b1p[n] - m1p[n]) * sc;
#pragma unroll
      for (int r = 0; r < 4; ++r) {
        float v = fmaxf((ha[r] + hb[r]) * sc + sh, 0.f);
        h1_s[((l >> 4) * 4 + r) * 264 + n] = f2b(v);
      }
    }
  }
  __syncthreads();   // barrier 5

  // layer 2: 256 -> 128, 1 n-tile per wave
  {
    int n0 = w * 16;
    const unsigned short* wp = w2t + (size_t)(n0 + m16) * 256 + qoff;
    int ar = (m16 & 7) * 264 + qoff;
    f32x4 ha = {0.f, 0.f, 0.f, 0.f}, hb = {0.f, 0.f, 0.f, 0.f};
#pragma unroll
    for (int kc = 0; kc < 8; ++kc) {
      bf16x8 av = *(const bf16x8*)&h1_s[ar + kc * 32];
      bf16x8 bv = *(const bf16x8*)(wp + kc * 32);
      if (kc & 1) hb = MFMA(av, bv, hb, 0, 0, 0);
      else        ha = MFMA(av, bv, ha, 0, 0, 0);
    }
    if (l < 32) {
      int n = n0 + m16;
      float sc = g2p[n] * rsqrtf(v2p[n] + BN_EPS);
      float sh = be2p[n] + (b2p[n] - m2p[n]) * sc;
#pragma unroll
      for (int r = 0; r < 4; ++r) {
        float v = fmaxf((ha[r] + hb[r]) * sc + sh, 0.f);
        h2_s[((l >> 4) * 4 + r) * 136 + n] = f2b(v);
      }
    }
  }
  __syncthreads();   // barrier 6

  // output: sigmoid(h2 @ Wout + bout)
  if (t < 64) {
    int bb = t >> 3, seg = t & 7;
    float a = 0.f;
#pragma unroll
    for (int j = 0; j < 16; ++j) {
      int k = seg * 16 + j;
      a += bs2f(h2_s[bb * 136 + k]) * Wout[k];
    }
    a += __shfl_xor(a, 4); a += __shfl_xor(a, 2); a += __shfl_xor(a, 1);
    if (seg == 0) out[b0 + bb] = 1.f / (1.f + expf(-(a + boutp[0])));
  }
}

// ===========================================================================
extern "C" void kernel_launch(void* const* d_in, const int* in_sizes, int n_in,
                              void* d_out, int out_size, void* d_ws, size_t ws_size,
                              hipStream_t stream)
{
  (void)in_sizes; (void)n_in; (void)out_size; (void)ws_size;
  unsigned short* ws = (unsigned short*)d_ws;

  prep<<<292, 256, 0, stream>>>(
      (const float*)d_in[3], (const float*)d_in[5], (const float*)d_in[6],
      (const float*)d_in[12], (const float*)d_in[18], ws);

  pnn_main<<<B / ROWS, 512, 0, stream>>>(
      (const float*)d_in[0], (const int*)d_in[1], (const float*)d_in[2],
      (const float*)d_in[4], ws,
      (const float*)d_in[7],  (const float*)d_in[8],  (const float*)d_in[9],
      (const float*)d_in[10], (const float*)d_in[11],
      (const float*)d_in[13], (const float*)d_in[14], (const float*)d_in[15],
      (const float*)d_in[16], (const float*)d_in[17],
      (const float*)d_in[19], (const float*)d_in[20], (const float*)d_in[21],
      (const float*)d_in[22], (const float*)d_in[23],
      (const float*)d_in[24], (const float*)d_in[25],
      (float*)d_out);
}

// Round 12
// 172.559 us; speedup vs baseline: 1.4198x; 1.3247x over previous
//
#include <hip/hip_runtime.h>
#include <hip/hip_bf16.h>
#include <math.h>

#define B 4096
#define NF 50
#define BN_EPS 1e-3f
#define ROWS 16

typedef float f32x4 __attribute__((ext_vector_type(4)));
typedef __bf16 bf16x8 __attribute__((ext_vector_type(8)));
#define MFMA __builtin_amdgcn_mfma_f32_16x16x32_bf16

__device__ __forceinline__ unsigned short f2b(float x) {
  unsigned u = __float_as_uint(x);
  return (unsigned short)((u + 0x7FFFu + ((u >> 16) & 1u)) >> 16);  // RNE
}
__device__ __forceinline__ unsigned packbf(float a, float b) {
  return ((unsigned)f2b(b) << 16) | (unsigned)f2b(a);
}
__device__ __forceinline__ float bs2f(unsigned short u) {
  return __uint_as_float(((unsigned)u) << 16);
}

// ---- workspace (unsigned short elems), all B-operands n-major/k-contig ----
#define WS_LS  0        // [64][3200]
#define WS_QW  204800   // [64][4096]
#define WS_W0  466944   // [512][192]
#define WS_W1  565248   // [256][512]
#define WS_W2  696320   // [128][256]

// ===========================================================================
// prep (proven): bf16 convert + W transposes via LDS tiles
__global__ __launch_bounds__(256) void prep(
    const float* __restrict__ ls, const float* __restrict__ qw,
    const float* __restrict__ W0, const float* __restrict__ W1,
    const float* __restrict__ W2, unsigned short* __restrict__ ws)
{
  int bid = blockIdx.x, t = threadIdx.x;
  if (bid < 228) {                // ls (100 blocks) + qw (128 blocks)
    int o = (bid * 256 + t) * 8;
    const float* src = (o < 204800) ? (ls + o) : (qw + (o - 204800));
    float4 a = *(const float4*)src, b = *(const float4*)(src + 4);
    int4 v = {(int)packbf(a.x, a.y), (int)packbf(a.z, a.w),
              (int)packbf(b.x, b.y), (int)packbf(b.z, b.w)};
    *(int4*)&ws[o] = v;
    return;
  }
  __shared__ unsigned short sh[64 * 72];
  int id = bid - 228;
  const float* W; int K, Ncols, kt, nt, wofs;
  if (id < 24)      { W = W0; K = 192; Ncols = 512; kt = id >> 3; nt = id & 7;  wofs = WS_W0; }
  else if (id < 56) { int j = id - 24; W = W1; K = 512; Ncols = 256; kt = j >> 2; nt = j & 3; wofs = WS_W1; }
  else              { int j = id - 56; W = W2; K = 256; Ncols = 128; kt = j >> 1; nt = j & 1; wofs = WS_W2; }
  int k0 = kt * 64, n0 = nt * 64;
  {
    int r = t >> 2, cs = (t & 3) * 16;
    const float* src = W + (size_t)(k0 + r) * Ncols + n0 + cs;
    float4 a = *(const float4*)src, b = *(const float4*)(src + 4);
    float4 c = *(const float4*)(src + 8), d = *(const float4*)(src + 12);
    unsigned short* dst = &sh[r * 72 + cs];
    *(int4*)dst = int4{(int)packbf(a.x, a.y), (int)packbf(a.z, a.w),
                       (int)packbf(b.x, b.y), (int)packbf(b.z, b.w)};
    *(int4*)(dst + 8) = int4{(int)packbf(c.x, c.y), (int)packbf(c.z, c.w),
                             (int)packbf(d.x, d.y), (int)packbf(d.z, d.w)};
  }
  __syncthreads();
  {
    int nr = t >> 2, ks = (t & 3) * 16;
    unsigned short vbuf[16];
#pragma unroll
    for (int j = 0; j < 16; ++j) vbuf[j] = sh[(ks + j) * 72 + nr];
    unsigned short* dst = &ws[wofs + (size_t)(n0 + nr) * K + k0 + ks];
    *(int4*)dst = *(int4*)&vbuf[0];
    *(int4*)(dst + 8) = *(int4*)&vbuf[8];
  }
}

// ===========================================================================
// r9 structure (256 blocks x 512 threads, 16 rows, 6 barriers) + explicit
// load BATCHING: every K-loop issues 10-20 independent loads into registers
// before first consume, amortizing L2 latency per group instead of per load.
__global__ __launch_bounds__(512) void pnn_main(
    const float* __restrict__ fv, const int* __restrict__ idx,
    const float* __restrict__ emb, const float* __restrict__ theta,
    const unsigned short* __restrict__ ws,
    const float* __restrict__ b0p, const float* __restrict__ g0p,
    const float* __restrict__ be0p, const float* __restrict__ m0p,
    const float* __restrict__ v0p,
    const float* __restrict__ b1p, const float* __restrict__ g1p,
    const float* __restrict__ be1p, const float* __restrict__ m1p,
    const float* __restrict__ v1p,
    const float* __restrict__ b2p, const float* __restrict__ g2p,
    const float* __restrict__ be2p, const float* __restrict__ m2p,
    const float* __restrict__ v2p,
    const float* __restrict__ Wout, const float* __restrict__ boutp,
    float* __restrict__ out)
{
  __shared__ unsigned short feats[25 * 16 * 136];  // 108.8 KB; aliased later
  __shared__ int   idx_s[ROWS * NF];
  __shared__ float fv_s[ROWS * NF];
  __shared__ float th2_s[64 * NF];
  __shared__ float s_s[ROWS * 68];
  __shared__ float sq_s[ROWS * 64];
  __shared__ unsigned short x_s[ROWS * 200];       // [16][192+8]

  unsigned short* h0_s = feats;                    // [16][520]
  unsigned short* h1_s = feats + 8320;             // [16][264]
  unsigned short* h2_s = feats + 12544;            // [16][136]

  const unsigned short* lsb = ws + WS_LS;
  const unsigned short* qwb = ws + WS_QW;
  const unsigned short* w0t = ws + WS_W0;
  const unsigned short* w1t = ws + WS_W1;
  const unsigned short* w2t = ws + WS_W2;

  const int t    = threadIdx.x;
  const int w    = t >> 6;          // wave 0..7
  const int l    = t & 63;
  const int m16  = l & 15;
  const int qoff = (l >> 4) * 8;
  const int b0   = blockIdx.x * ROWS;

  // ---------------- phase 0: idx/fv/theta^2 ----------------
  for (int i = t; i < ROWS * NF; i += 512) {
    idx_s[i] = idx[b0 * NF + i];
    fv_s[i]  = fv[b0 * NF + i];
  }
  for (int i = t; i < 64 * NF; i += 512) { float v = theta[i]; th2_s[i] = v * v; }
  __syncthreads();   // barrier 1

  // ---------------- phase 1: gather feats, s, sq (batched loads) ----------
  {
    const int row = t >> 5;          // half-wave = one batch row
    const int m2  = (t & 31) * 2;    // two m columns per lane
    float s0 = 0.f, s1 = 0.f;
    for (int g = 0; g < 5; ++g) {    // 5 groups x 5 chunks (10 loads in flight)
      float2 e[10];
#pragma unroll
      for (int j = 0; j < 5; ++j) {
        int n0 = (g * 5 + j) * 2;
        int iv0 = idx_s[row * NF + n0], iv1 = idx_s[row * NF + n0 + 1];
        e[2 * j]     = *(const float2*)(emb + (size_t)iv0 * 64 + m2);
        e[2 * j + 1] = *(const float2*)(emb + (size_t)iv1 * 64 + m2);
      }
#pragma unroll
      for (int j = 0; j < 5; ++j) {
        int c = g * 5 + j;
        int n0 = 2 * c, n1 = n0 + 1;
        float f0 = fv_s[row * NF + n0], f1 = fv_s[row * NF + n1];
        float p00 = f0 * e[2 * j].x,     p01 = f0 * e[2 * j].y;
        float p10 = f1 * e[2 * j + 1].x, p11 = f1 * e[2 * j + 1].y;
        unsigned short* fc = feats + c * 2176 + row * 136;
        *(unsigned*)&fc[m2]      = packbf(p00, p01);
        *(unsigned*)&fc[64 + m2] = packbf(p10, p11);
        s0 += p00 + p10; s1 += p01 + p11;
        float q0 = p00 * p00 + p01 * p01;
        float q1 = p10 * p10 + p11 * p11;
        q0 += __shfl_xor(q0, 16); q0 += __shfl_xor(q0, 8); q0 += __shfl_xor(q0, 4);
        q0 += __shfl_xor(q0, 2);  q0 += __shfl_xor(q0, 1);
        q1 += __shfl_xor(q1, 16); q1 += __shfl_xor(q1, 8); q1 += __shfl_xor(q1, 4);
        q1 += __shfl_xor(q1, 2);  q1 += __shfl_xor(q1, 1);
        if ((t & 31) == 0) { sq_s[row * 64 + n0] = q0; sq_s[row * 64 + n1] = q1; }
      }
    }
    float2 sv; sv.x = s0; sv.y = s1;
    *(float2*)&s_s[row * 68 + m2] = sv;
  }
  __syncthreads();   // barrier 2

  // ---------------- phase 2: independent per-wave GEMMs (batched B) -------
  if (w < 4) {
    // l_z: d-tile [16w,16w+16), K=3200; 5 groups x 5 chunks, 20 B-frags/group
    const int dt = w;
    f32x4 a0v = {0.f, 0.f, 0.f, 0.f}, a1v = {0.f, 0.f, 0.f, 0.f};
    const unsigned short* lp0 = lsb + (size_t)(dt * 16 + m16) * 3200 + qoff;
    const int arow = m16 * 136 + qoff;
    for (int g = 0; g < 5; ++g) {
      bf16x8 bv[20];
#pragma unroll
      for (int cc = 0; cc < 5; ++cc) {
        const unsigned short* lp = lp0 + (g * 5 + cc) * 128;
#pragma unroll
        for (int s4 = 0; s4 < 4; ++s4)
          bv[cc * 4 + s4] = *(const bf16x8*)(lp + s4 * 32);
      }
#pragma unroll
      for (int cc = 0; cc < 5; ++cc) {
        const unsigned short* fc = feats + (g * 5 + cc) * 2176 + arow;
#pragma unroll
        for (int s4 = 0; s4 < 4; ++s4) {
          bf16x8 av = *(const bf16x8*)(fc + s4 * 32);
          if (s4 & 1) a1v = MFMA(av, bv[cc * 4 + s4], a1v, 0, 0, 0);
          else        a0v = MFMA(av, bv[cc * 4 + s4], a0v, 0, 0, 0);
        }
      }
    }
#pragma unroll
    for (int r = 0; r < 4; ++r)
      x_s[((l >> 4) * 4 + r) * 200 + dt * 16 + m16] = f2b(a0v[r] + a1v[r]);
    // l_p_in from LDS th2
    {
      int d = dt * 16 + m16;
      float acc[4] = {0.f, 0.f, 0.f, 0.f};
      for (int n = 0; n < NF; ++n) {
        float th2 = th2_s[d * NF + n];
#pragma unroll
        for (int r = 0; r < 4; ++r)
          acc[r] += sq_s[((l >> 4) * 4 + r) * 64 + n] * th2;
      }
#pragma unroll
      for (int r = 0; r < 4; ++r)
        x_s[((l >> 4) * 4 + r) * 200 + 64 + d] = f2b(acc[r]);
    }
  } else {
    // l_p_out: K=4096, P in-register; 8 groups x 8 m, 16 B-frags/group
    const int dt = w - 4;
    const int row = m16;
    const int nb = qoff;
    float sn[16];
    *(float4*)&sn[0]  = *(const float4*)&s_s[row * 68 + nb];
    *(float4*)&sn[4]  = *(const float4*)&s_s[row * 68 + nb + 4];
    *(float4*)&sn[8]  = *(const float4*)&s_s[row * 68 + 32 + nb];
    *(float4*)&sn[12] = *(const float4*)&s_s[row * 68 + 32 + nb + 4];
    f32x4 a0v = {0.f, 0.f, 0.f, 0.f}, a1v = {0.f, 0.f, 0.f, 0.f};
    const unsigned short* qp0 = qwb + (size_t)(dt * 16 + m16) * 4096 + qoff;
    for (int g = 0; g < 8; ++g) {
      bf16x8 bv[16];
#pragma unroll
      for (int mi = 0; mi < 8; ++mi) {
        const unsigned short* qp = qp0 + (g * 8 + mi) * 64;
        bv[2 * mi]     = *(const bf16x8*)qp;
        bv[2 * mi + 1] = *(const bf16x8*)(qp + 32);
      }
#pragma unroll
      for (int mi = 0; mi < 8; ++mi) {
        float sm = s_s[row * 68 + g * 8 + mi];
        union { unsigned u[4]; bf16x8 v; } af0, af1;
#pragma unroll
        for (int j = 0; j < 4; ++j) {
          af0.u[j] = packbf(sm * sn[2 * j],     sm * sn[2 * j + 1]);
          af1.u[j] = packbf(sm * sn[8 + 2 * j], sm * sn[8 + 2 * j + 1]);
        }
        a0v = MFMA(af0.v, bv[2 * mi],     a0v, 0, 0, 0);
        a1v = MFMA(af1.v, bv[2 * mi + 1], a1v, 0, 0, 0);
      }
    }
#pragma unroll
    for (int r = 0; r < 4; ++r)
      x_s[((l >> 4) * 4 + r) * 200 + 128 + dt * 16 + m16] = f2b(a0v[r] + a1v[r]);
  }
  __syncthreads();   // barrier 3 (feats dead; h-buffers alias it)

  // ---------------- phase 3: MLP (batched W-frags) ----------------
  // layer 0: 192 -> 512, 4 n-tiles per wave, 6 frags batched per tile
  {
    int ar = m16 * 200 + qoff;
    bf16x8 xa[6];
#pragma unroll
    for (int kc = 0; kc < 6; ++kc) xa[kc] = *(const bf16x8*)&x_s[ar + kc * 32];
    for (int j = 0; j < 4; ++j) {
      int n0 = (w * 4 + j) * 16;
      const unsigned short* wp = w0t + (size_t)(n0 + m16) * 192 + qoff;
      bf16x8 bv[6];
#pragma unroll
      for (int kc = 0; kc < 6; ++kc) bv[kc] = *(const bf16x8*)(wp + kc * 32);
      f32x4 ha = {0.f, 0.f, 0.f, 0.f}, hb = {0.f, 0.f, 0.f, 0.f};
#pragma unroll
      for (int kc = 0; kc < 6; ++kc) {
        if (kc & 1) hb = MFMA(xa[kc], bv[kc], hb, 0, 0, 0);
        else        ha = MFMA(xa[kc], bv[kc], ha, 0, 0, 0);
      }
      int n = n0 + m16;
      float sc = g0p[n] * rsqrtf(v0p[n] + BN_EPS);
      float sh = be0p[n] + (b0p[n] - m0p[n]) * sc;
#pragma unroll
      for (int r = 0; r < 4; ++r) {
        float v = fmaxf((ha[r] + hb[r]) * sc + sh, 0.f);
        h0_s[((l >> 4) * 4 + r) * 520 + n] = f2b(v);
      }
    }
  }
  __syncthreads();   // barrier 4

  // layer 1: 512 -> 256, 2 n-tiles per wave, 16 frags batched
  for (int j = 0; j < 2; ++j) {
    int n0 = (w * 2 + j) * 16;
    const unsigned short* wp = w1t + (size_t)(n0 + m16) * 512 + qoff;
    bf16x8 bv[16];
#pragma unroll
    for (int kc = 0; kc < 16; ++kc) bv[kc] = *(const bf16x8*)(wp + kc * 32);
    int ar = m16 * 520 + qoff;
    f32x4 ha = {0.f, 0.f, 0.f, 0.f}, hb = {0.f, 0.f, 0.f, 0.f};
#pragma unroll
    for (int kc = 0; kc < 16; ++kc) {
      bf16x8 av = *(const bf16x8*)&h0_s[ar + kc * 32];
      if (kc & 1) hb = MFMA(av, bv[kc], hb, 0, 0, 0);
      else        ha = MFMA(av, bv[kc], ha, 0, 0, 0);
    }
    int n = n0 + m16;
    float sc = g1p[n] * rsqrtf(v1p[n] + BN_EPS);
    float sh = be1p[n] + (b1p[n] - m1p[n]) * sc;
#pragma unroll
    for (int r = 0; r < 4; ++r) {
      float v = fmaxf((ha[r] + hb[r]) * sc + sh, 0.f);
      h1_s[((l >> 4) * 4 + r) * 264 + n] = f2b(v);
    }
  }
  __syncthreads();   // barrier 5

  // layer 2: 256 -> 128, 1 n-tile per wave, 8 frags batched
  {
    int n0 = w * 16;
    const unsigned short* wp = w2t + (size_t)(n0 + m16) * 256 + qoff;
    bf16x8 bv[8];
#pragma unroll
    for (int kc = 0; kc < 8; ++kc) bv[kc] = *(const bf16x8*)(wp + kc * 32);
    int ar = m16 * 264 + qoff;
    f32x4 ha = {0.f, 0.f, 0.f, 0.f}, hb = {0.f, 0.f, 0.f, 0.f};
#pragma unroll
    for (int kc = 0; kc < 8; ++kc) {
      bf16x8 av = *(const bf16x8*)&h1_s[ar + kc * 32];
      if (kc & 1) hb = MFMA(av, bv[kc], hb, 0, 0, 0);
      else        ha = MFMA(av, bv[kc], ha, 0, 0, 0);
    }
    int n = n0 + m16;
    float sc = g2p[n] * rsqrtf(v2p[n] + BN_EPS);
    float sh = be2p[n] + (b2p[n] - m2p[n]) * sc;
#pragma unroll
    for (int r = 0; r < 4; ++r) {
      float v = fmaxf((ha[r] + hb[r]) * sc + sh, 0.f);
      h2_s[((l >> 4) * 4 + r) * 136 + n] = f2b(v);
    }
  }
  __syncthreads();   // barrier 6

  // output: sigmoid(h2 @ Wout + bout)
  if (t < 128) {
    int bb = t >> 3, seg = t & 7;
    float a = 0.f;
#pragma unroll
    for (int j = 0; j < 16; ++j) {
      int k = seg * 16 + j;
      a += bs2f(h2_s[bb * 136 + k]) * Wout[k];
    }
    a += __shfl_xor(a, 4); a += __shfl_xor(a, 2); a += __shfl_xor(a, 1);
    if (seg == 0) out[b0 + bb] = 1.f / (1.f + expf(-(a + boutp[0])));
  }
}

// ===========================================================================
extern "C" void kernel_launch(void* const* d_in, const int* in_sizes, int n_in,
                              void* d_out, int out_size, void* d_ws, size_t ws_size,
                              hipStream_t stream)
{
  (void)in_sizes; (void)n_in; (void)out_size; (void)ws_size;
  unsigned short* ws = (unsigned short*)d_ws;

  prep<<<292, 256, 0, stream>>>(
      (const float*)d_in[3], (const float*)d_in[5], (const float*)d_in[6],
      (const float*)d_in[12], (const float*)d_in[18], ws);

  pnn_main<<<B / ROWS, 512, 0, stream>>>(
      (const float*)d_in[0], (const int*)d_in[1], (const float*)d_in[2],
      (const float*)d_in[4], ws,
      (const float*)d_in[7],  (const float*)d_in[8],  (const float*)d_in[9],
      (const float*)d_in[10], (const float*)d_in[11],
      (const float*)d_in[13], (const float*)d_in[14], (const float*)d_in[15],
      (const float*)d_in[16], (const float*)d_in[17],
      (const float*)d_in[19], (const float*)d_in[20], (const float*)d_in[21],
      (const float*)d_in[22], (const float*)d_in[23],
      (const float*)d_in[24], (const float*)d_in[25],
      (float*)d_out);
}